// Round 13
// baseline (79.957 us; speedup 1.0000x reference)
//
#include <hip/hip_runtime.h>
#include <hip/hip_bf16.h>

// out[b,h,t,f] = sum_{r=0..64} a[b,h,t,r] * v[b,h, t+r-32, f]  (zero-padded in t)
// B=8 H=16 T=4096 F=64 R=65, fp32 in/out. bf16 MFMA (absmax 0.25 vs thr 1.0).
//
// Round 13 = round 11 (best, 69.7us) + native bf16 casts. r12's explicit load
// pipeline was defeated by the compiler (VGPR stayed 32, loads re-sunk) and
// regressed FETCH; abandoned. The hand-written RNE bit-twiddle f2bf blocked
// v_cvt_pk_bf16_f32 fusion (m240: scalar casts > hand-written) — ~150 VALU/wave
// in the hot MFMA phase drops ~4x with native __float2bfloat16.
//   OUT(32x64) = Ablk(32x96) x Vslice(96x64),
//   Ablk[i][c] = (0<=c-i<=64) ? a[t0+32wr+i][c-i] : 0   (band, LDS-densified)
//   B[k][col]: lane(n,hi) elem j <- v[t0+32wr-32+16kb+8hi+j][32wc+n]

#define TT 4096
#define RRR 65
#define FF 64
#define SA_S 100     // bf16 row stride: 200B rows -> 2-way (free) on A b128 reads

typedef short bf16x8 __attribute__((ext_vector_type(8)));
typedef float f32x16 __attribute__((ext_vector_type(16)));

__device__ __forceinline__ unsigned short bfbits(float x) {
    union { __hip_bfloat16 h; unsigned short u; } c;
    c.h = __float2bfloat16(x);                 // compiler fuses pairs to v_cvt_pk
    return c.u;
}
__device__ __forceinline__ unsigned pk2(float lo, float hi) {
    return (unsigned)bfbits(lo) | ((unsigned)bfbits(hi) << 16);
}

// Barrier with LDS-only drain: global loads/stores stay in flight (no vmcnt).
#define BAR() do {                                                             \
    asm volatile("s_waitcnt lgkmcnt(0)" ::: "memory");                         \
    __builtin_amdgcn_sched_barrier(0);                                         \
    __builtin_amdgcn_s_barrier();                                              \
    __builtin_amdgcn_sched_barrier(0);                                         \
} while (0)

__global__ __launch_bounds__(256, 8)
void unfold_mfma(const float* __restrict__ a, const float* __restrict__ v,
                 float* __restrict__ out) {
    __shared__ __align__(16) unsigned short sa[64 * SA_S];   // 12800 B

    const int tid = threadIdx.x;
    const int f   = tid & 63;
    const int wv  = tid >> 6;
    const int n   = f & 31;
    const int hi  = f >> 5;
    const int wr  = wv >> 1;
    const int wc  = wv & 1;
    const int Rw  = 32 * wr + n;

    // ---- bijective XCD swizzle: each XCD owns 16 whole (b,h) slabs ----
    const int lid = ((blockIdx.x & 7) << 10) | (blockIdx.x >> 3);
    const int bh = lid >> 6;                    // 64 tiles per (b,h)
    const int t0 = (lid & 63) << 6;

    const float* arow = a + ((size_t)bh * TT + t0) * RRR;
    const float* vsl  = v + (size_t)bh * TT * FF;

    // ---- issue a loads early (latency hides under prefill + barrier) ----
    float4 aq[4];
    #pragma unroll
    for (int it = 0; it < 4; ++it) {
        int lin = tid + it * 256;
        if (lin < 64 * 15) {
            int R = lin / 15, j = lin - R * 15;
            int r0 = (4 - (R & 3)) & 3;
            aq[it] = *(const float4*)(arow + (size_t)R * RRR + r0 + 4 * j);
        }
    }
    float ae[2];
    #pragma unroll
    for (int it = 0; it < 2; ++it) {
        int lin = tid + it * 256;
        if (lin < 64 * 5) {
            int R = lin / 5, e = lin - R * 5;
            int r0 = (4 - (R & 3)) & 3;
            int r = (e < r0) ? e : 60 + e;      // head [0,r0) + tail [r0+60,64]
            ae[it] = arow[(size_t)R * RRR + r];
        }
    }

    // ---- zero-prefill sa (band complement must be 0) ----
    {
        uint4 z = make_uint4(0, 0, 0, 0);
        uint4* sp = (uint4*)sa;
        #pragma unroll
        for (int it = 0; it < 4; ++it) {
            int lin = tid + it * 256;
            if (lin < (64 * SA_S) / 8) sp[lin] = z;
        }
    }
    BAR();

    // ---- scatter a band: sa[R][(R&31) + r] = bf16(a[t0+R][r]) ----
    #pragma unroll
    for (int it = 0; it < 4; ++it) {
        int lin = tid + it * 256;
        if (lin < 64 * 15) {
            int R = lin / 15, j = lin - R * 15;
            int r0 = (4 - (R & 3)) & 3;
            int rq = r0 + 4 * j;
            float4 q = aq[it];
            uint2 pw; pw.x = pk2(q.x, q.y); pw.y = pk2(q.z, q.w);
            *(uint2*)&sa[R * SA_S + (R & 31) + rq] = pw;   // (R&31)+rq ≡ 0 mod 4
        }
    }
    #pragma unroll
    for (int it = 0; it < 2; ++it) {
        int lin = tid + it * 256;
        if (lin < 64 * 5) {
            int R = lin / 5, e = lin - R * 5;
            int r0 = (4 - (R & 3)) & 3;
            int r = (e < r0) ? e : 60 + e;
            sa[R * SA_S + (R & 31) + r] = bfbits(ae[it]);
        }
    }
    BAR();

    // ---- MFMA: B fragments straight from global v (coalesced 2x128B/instr) ----
    const int fcol = 32 * wc + n;
    const int tb   = t0 + 32 * wr - 32 + 8 * hi;   // t for (kb=0, j=0)
    const float* vp = vsl + fcol;

    f32x16 acc = {};
    if (t0 >= 32 && t0 + 96 <= TT) {               // interior: 62 of 64 tiles
        #pragma unroll
        for (int kb = 0; kb < 6; ++kb) {
            float x[8];
            #pragma unroll
            for (int j = 0; j < 8; ++j)
                x[j] = vp[(size_t)(tb + 16 * kb + j) * FF];
            union { bf16x8 v8; unsigned u[4]; } bu;
            bu.u[0] = pk2(x[0], x[1]); bu.u[1] = pk2(x[2], x[3]);
            bu.u[2] = pk2(x[4], x[5]); bu.u[3] = pk2(x[6], x[7]);
            bf16x8 af = *(const bf16x8*)&sa[Rw * SA_S + kb * 16 + hi * 8];
            acc = __builtin_amdgcn_mfma_f32_32x32x16_bf16(af, bu.v8, acc, 0, 0, 0);
        }
    } else {                                       // t-boundary tiles
        #pragma unroll
        for (int kb = 0; kb < 6; ++kb) {
            float x[8];
            #pragma unroll
            for (int j = 0; j < 8; ++j) {
                int t = tb + 16 * kb + j;
                x[j] = (t >= 0 && t < TT) ? vp[(size_t)t * FF] : 0.f;
            }
            union { bf16x8 v8; unsigned u[4]; } bu;
            bu.u[0] = pk2(x[0], x[1]); bu.u[1] = pk2(x[2], x[3]);
            bu.u[2] = pk2(x[4], x[5]); bu.u[3] = pk2(x[6], x[7]);
            bf16x8 af = *(const bf16x8*)&sa[Rw * SA_S + kb * 16 + hi * 8];
            acc = __builtin_amdgcn_mfma_f32_32x32x16_bf16(af, bu.v8, acc, 0, 0, 0);
        }
    }

    // ---- store: C/D col = lane&31, row = (reg&3) + 8*(reg>>2) + 4*(lane>>5) ----
    float* op = out + (size_t)bh * TT * FF + (size_t)(t0 + 32 * wr) * FF + 32 * wc;
    #pragma unroll
    for (int reg = 0; reg < 16; ++reg) {
        int row = (reg & 3) + 8 * (reg >> 2) + 4 * hi;
        __builtin_nontemporal_store(acc[reg], &op[row * FF + n]);
    }
}

extern "C" void kernel_launch(void* const* d_in, const int* in_sizes, int n_in,
                              void* d_out, int out_size, void* d_ws, size_t ws_size,
                              hipStream_t stream) {
    const float* a = (const float*)d_in[0];
    const float* v = (const float*)d_in[1];
    float* out = (float*)d_out;

    const int BH = in_sizes[1] / (TT * FF);      // 128
    const int grid = BH * 64;                    // 8192 single-tile blocks

    unfold_mfma<<<grid, 256, 0, stream>>>(a, v, out);
}

// Round 14
// 69.637 us; speedup vs baseline: 1.1482x; 1.1482x over previous
//
#include <hip/hip_runtime.h>

// out[b,h,t,f] = sum_{r=0..64} a[b,h,t,r] * v[b,h, t+r-32, f]  (zero-padded in t)
// B=8 H=16 T=4096 F=64 R=65, fp32 in/out. bf16 MFMA (absmax 0.25 vs thr 1.0).
//
// Round 14 = round 11 (best, 69.7us) with the block DOUBLED: 512 thr / 8 waves /
// TILE=128 rows. Per-wave code, v access pattern, sa mapping and VGPR pressure
// identical to r11; per-CU block-prologue count and barrier count per output
// halve (4 blocks x 8 waves = same 32 waves/CU; LDS 25.6KB x 4 = 102KB fits).
// r12 (explicit load pipeline) and r13 (native casts) both regressed -> r11
// body kept byte-for-byte, including the RNE bit-twiddle f2bf.
//   OUT(32x64) = Ablk(32x96) x Vslice(96x64), per wave (wr,wc)
//   Ablk[i][c] = (0<=c-i<=64) ? a[t0+32wr+i][c-i] : 0   (band, LDS-densified)
//   B[k][col]: lane(n,hi) elem j <- v[t0+32wr-32+16kb+8hi+j][32wc+n]

#define TT 4096
#define RRR 65
#define FF 64
#define TILE 128
#define SA_S 100     // bf16 row stride: 200B rows -> 2-way (free) on A b128 reads

typedef short bf16x8 __attribute__((ext_vector_type(8)));
typedef float f32x16 __attribute__((ext_vector_type(16)));

__device__ __forceinline__ unsigned short f2bf(float x) {
    unsigned int u = __float_as_uint(x);
    u += 0x7fff + ((u >> 16) & 1);            // RNE
    return (unsigned short)(u >> 16);
}
__device__ __forceinline__ unsigned pk2(float lo, float hi) {
    return (unsigned)f2bf(lo) | ((unsigned)f2bf(hi) << 16);
}

// Barrier with LDS-only drain: global loads/stores stay in flight (no vmcnt).
#define BAR() do {                                                             \
    asm volatile("s_waitcnt lgkmcnt(0)" ::: "memory");                         \
    __builtin_amdgcn_sched_barrier(0);                                         \
    __builtin_amdgcn_s_barrier();                                              \
    __builtin_amdgcn_sched_barrier(0);                                         \
} while (0)

__global__ __launch_bounds__(512, 8)
void unfold_mfma(const float* __restrict__ a, const float* __restrict__ v,
                 float* __restrict__ out) {
    __shared__ __align__(16) unsigned short sa[TILE * SA_S];   // 25600 B

    const int tid = threadIdx.x;
    const int f   = tid & 63;
    const int wv  = tid >> 6;          // 0..7
    const int n   = f & 31;
    const int hi  = f >> 5;
    const int wr  = wv >> 1;           // 0..3: row quadrant
    const int wc  = wv & 1;            // col half
    const int Rw  = 32 * wr + n;       // sa row; Rw&31 == n (band mapping holds)

    // ---- bijective XCD swizzle: 4096 blocks, each XCD owns 512 consecutive
    //      logical blocks = 16 whole (b,h) slabs -> v window L2-resident ----
    const int lid = ((blockIdx.x & 7) << 9) | (blockIdx.x >> 3);
    const int bh = lid >> 5;                    // 32 tiles per (b,h)
    const int t0 = (lid & 31) << 7;

    const float* arow = a + ((size_t)bh * TT + t0) * RRR;
    const float* vsl  = v + (size_t)bh * TT * FF;

    // ---- issue a loads early (latency hides under prefill + barrier) ----
    float4 aq[4];
    #pragma unroll
    for (int it = 0; it < 4; ++it) {
        int lin = tid + it * 512;
        if (lin < TILE * 15) {
            int R = lin / 15, j = lin - R * 15;
            int r0 = (4 - (R & 3)) & 3;
            aq[it] = *(const float4*)(arow + (size_t)R * RRR + r0 + 4 * j);
        }
    }
    float ae[2];
    #pragma unroll
    for (int it = 0; it < 2; ++it) {
        int lin = tid + it * 512;
        if (lin < TILE * 5) {
            int R = lin / 5, e = lin - R * 5;
            int r0 = (4 - (R & 3)) & 3;
            int r = (e < r0) ? e : 60 + e;      // head [0,r0) + tail [r0+60,64]
            ae[it] = arow[(size_t)R * RRR + r];
        }
    }

    // ---- zero-prefill sa (band complement must be 0): 3200 uint4 ----
    {
        uint4 z = make_uint4(0, 0, 0, 0);
        uint4* sp = (uint4*)sa;
        #pragma unroll
        for (int it = 0; it < 4; ++it) {
            int lin = tid + it * 512;
            if (lin < (TILE * SA_S) / 8) sp[lin] = z;
        }
    }
    BAR();

    // ---- scatter a band: sa[R][(R&31) + r] = bf16(a[t0+R][r]) ----
    #pragma unroll
    for (int it = 0; it < 4; ++it) {
        int lin = tid + it * 512;
        if (lin < TILE * 15) {
            int R = lin / 15, j = lin - R * 15;
            int r0 = (4 - (R & 3)) & 3;
            int rq = r0 + 4 * j;
            float4 q = aq[it];
            uint2 pw; pw.x = pk2(q.x, q.y); pw.y = pk2(q.z, q.w);
            *(uint2*)&sa[R * SA_S + (R & 31) + rq] = pw;   // (R&31)+rq ≡ 0 mod 4
        }
    }
    #pragma unroll
    for (int it = 0; it < 2; ++it) {
        int lin = tid + it * 512;
        if (lin < TILE * 5) {
            int R = lin / 5, e = lin - R * 5;
            int r0 = (4 - (R & 3)) & 3;
            int r = (e < r0) ? e : 60 + e;
            sa[R * SA_S + (R & 31) + r] = f2bf(ae[it]);
        }
    }
    BAR();

    // ---- MFMA: B fragments straight from global v (coalesced 2x128B/instr) ----
    const int fcol = 32 * wc + n;
    const int tb   = t0 + 32 * wr - 32 + 8 * hi;   // t for (kb=0, j=0)
    const float* vp = vsl + fcol;

    f32x16 acc = {};
    if (t0 >= 32 && t0 + 192 <= TT) {              // interior: 30 of 32 tiles
        #pragma unroll
        for (int kb = 0; kb < 6; ++kb) {
            float x[8];
            #pragma unroll
            for (int j = 0; j < 8; ++j)
                x[j] = vp[(size_t)(tb + 16 * kb + j) * FF];
            union { bf16x8 v8; unsigned u[4]; } bu;
            bu.u[0] = pk2(x[0], x[1]); bu.u[1] = pk2(x[2], x[3]);
            bu.u[2] = pk2(x[4], x[5]); bu.u[3] = pk2(x[6], x[7]);
            bf16x8 af = *(const bf16x8*)&sa[Rw * SA_S + kb * 16 + hi * 8];
            acc = __builtin_amdgcn_mfma_f32_32x32x16_bf16(af, bu.v8, acc, 0, 0, 0);
        }
    } else {                                       // t-boundary tiles
        #pragma unroll
        for (int kb = 0; kb < 6; ++kb) {
            float x[8];
            #pragma unroll
            for (int j = 0; j < 8; ++j) {
                int t = tb + 16 * kb + j;
                x[j] = (t >= 0 && t < TT) ? vp[(size_t)t * FF] : 0.f;
            }
            union { bf16x8 v8; unsigned u[4]; } bu;
            bu.u[0] = pk2(x[0], x[1]); bu.u[1] = pk2(x[2], x[3]);
            bu.u[2] = pk2(x[4], x[5]); bu.u[3] = pk2(x[6], x[7]);
            bf16x8 af = *(const bf16x8*)&sa[Rw * SA_S + kb * 16 + hi * 8];
            acc = __builtin_amdgcn_mfma_f32_32x32x16_bf16(af, bu.v8, acc, 0, 0, 0);
        }
    }

    // ---- store: C/D col = lane&31, row = (reg&3) + 8*(reg>>2) + 4*(lane>>5) ----
    float* op = out + (size_t)bh * TT * FF + (size_t)(t0 + 32 * wr) * FF + 32 * wc;
    #pragma unroll
    for (int reg = 0; reg < 16; ++reg) {
        int row = (reg & 3) + 8 * (reg >> 2) + 4 * hi;
        __builtin_nontemporal_store(acc[reg], &op[row * FF + n]);
    }
}

extern "C" void kernel_launch(void* const* d_in, const int* in_sizes, int n_in,
                              void* d_out, int out_size, void* d_ws, size_t ws_size,
                              hipStream_t stream) {
    const float* a = (const float*)d_in[0];
    const float* v = (const float*)d_in[1];
    float* out = (float*)d_out;

    const int BH = in_sizes[1] / (TT * FF);      // 128
    const int grid = BH * (TT / TILE);           // 4096 blocks

    unfold_mfma<<<grid, 512, 0, stream>>>(a, v, out);
}